// Round 1
// baseline (414.911 us; speedup 1.0000x reference)
//
#include <hip/hip_runtime.h>
#include <hip/hip_bf16.h>

#define B_ 16
#define T_ 12
#define N_ 2048
#define C_ 64
#define NW_ 10
#define K_ 6144  // WIN*N

typedef __attribute__((ext_vector_type(8))) short bf16x8;
typedef __attribute__((ext_vector_type(4))) float f32x4;

__device__ __forceinline__ unsigned short f2bf(float f) {
  union { float f; unsigned int u; } v; v.f = f;
  unsigned int u = v.u;
  return (unsigned short)((u + 0x7FFFu + ((u >> 16) & 1u)) >> 16);  // RNE
}

// async global->LDS, 16B per lane. LDS dest is wave-uniform base + lane*16.
__device__ __forceinline__ void gload16(const void* g, void* l) {
  __builtin_amdgcn_global_load_lds(
      (const __attribute__((address_space(1))) unsigned int*)g,
      (__attribute__((address_space(3))) unsigned int*)l, 16, 0, 0);
}

// ---------------- prep: x = data + temb + semb -> bf16, layout [b][t][c][n] ----------------
__global__ __launch_bounds__(256) void prep_x(const float* __restrict__ data,
                                              const float* __restrict__ temb,
                                              const float* __restrict__ semb,
                                              unsigned short* __restrict__ xbt) {
  __shared__ __align__(16) unsigned short tile[64][136];  // [c][n_local], pitch mult of 8
  int blk = blockIdx.x;
  int nt = blk & 15;
  int t = (blk >> 4) % T_;
  int b = blk / (16 * T_);
  int n0 = nt * 128;
  int tid = threadIdx.x;
  int nl = tid >> 1, c0 = (tid & 1) * 32;
  int n = n0 + nl;
  const float* drow = data + ((size_t)(b * T_ + t) * N_ + n) * C_;
  const float* trow = temb + t * C_;
  const float* srow = semb + (size_t)n * C_;
  for (int cc = 0; cc < 32; cc += 4) {
    float4 v = *(const float4*)(drow + c0 + cc);
    float4 te = *(const float4*)(trow + c0 + cc);
    float4 se = *(const float4*)(srow + c0 + cc);
    tile[c0 + cc + 0][nl] = f2bf(v.x + te.x + se.x);
    tile[c0 + cc + 1][nl] = f2bf(v.y + te.y + se.y);
    tile[c0 + cc + 2][nl] = f2bf(v.z + te.z + se.z);
    tile[c0 + cc + 3][nl] = f2bf(v.w + te.w + se.w);
  }
  __syncthreads();
  unsigned short* xrow = xbt + (size_t)(b * T_ + t) * C_ * N_;
  for (int it = 0; it < 4; ++it) {
    int p = it * 256 + tid;
    int c = p >> 4, ng = p & 15;  // 16 lanes cover one contiguous 256B run
    uint4 v = *(const uint4*)&tile[c][ng * 8];
    *(uint4*)(xrow + (size_t)c * N_ + n0 + ng * 8) = v;
  }
}

// ---------------- prep: adj_mid rows [N..2N) -> bf16 [m][k] ----------------
__global__ __launch_bounds__(256) void prep_adj(const float* __restrict__ adj,
                                                unsigned short* __restrict__ adjb) {
  size_t i = ((size_t)blockIdx.x * 256 + threadIdx.x) * 8;  // grid covers 2048*6144 exactly
  const float* src = adj + (size_t)N_ * K_ + i;
  float4 a = *(const float4*)src;
  float4 b4 = *(const float4*)(src + 4);
  union { unsigned short s[8]; uint4 v; } pk;
  pk.s[0] = f2bf(a.x);  pk.s[1] = f2bf(a.y);  pk.s[2] = f2bf(a.z);  pk.s[3] = f2bf(a.w);
  pk.s[4] = f2bf(b4.x); pk.s[5] = f2bf(b4.y); pk.s[6] = f2bf(b4.z); pk.s[7] = f2bf(b4.w);
  *(uint4*)(adjb + i) = pk.v;
}

// ---------------- prep: W -> bf16 transposed [w][f][d][c] ----------------
__global__ __launch_bounds__(256) void prep_w(const float* __restrict__ W,
                                              unsigned short* __restrict__ wbt) {
  int idx = blockIdx.x * 256 + threadIdx.x;  // 960 blocks -> 245760 exactly
  int c = idx & 63;
  int d = (idx >> 6) & 127;
  int wf = idx >> 13;  // w*3+f
  float v = W[((size_t)wf * 64 + c) * 128 + d];
  wbt[idx] = f2bf(v);
}

// ---------------- main GEMM: agg[bw][m][c] = adj_mid[m][:] . wins[bw][:][c] ----------------
__global__ __launch_bounds__(256) void gemm_agg(const unsigned short* __restrict__ adjb,
                                                const unsigned short* __restrict__ xbt,
                                                unsigned short* __restrict__ aggb) {
  __shared__ __align__(16) unsigned short sA[128 * 64];  // [m][k] row=128B, chunk-swizzled
  __shared__ __align__(16) unsigned short sB[64 * 64];   // [c][k]
  int bm = blockIdx.x;   // 0..15
  int bw = blockIdx.y;   // 0..159
  int b = bw / NW_, w = bw % NW_;
  int tid = threadIdx.x, lane = tid & 63, wid = tid >> 6;
  int wm = wid >> 1, wn = wid & 1;
  f32x4 acc[4][2];
  for (int i = 0; i < 4; ++i)
    for (int j = 0; j < 2; ++j) acc[i][j] = (f32x4)0.f;

  const unsigned short* Abase = adjb + (size_t)bm * 128 * K_;
  const unsigned short* Xbase = xbt + (size_t)(b * T_ + w) * C_ * N_;
  int lrow8 = lane >> 3, jl = lane & 7;
  int l15 = lane & 15, l4 = lane >> 4;

  for (int k0 = 0; k0 < K_; k0 += 64) {
    __syncthreads();
    // stage A: 16 chunks of 1KB; source chunk pre-swizzled so LDS[row][j] = global j^(row&7)
    for (int ci = 0; ci < 4; ++ci) {
      int chunk = wid * 4 + ci;
      int row = chunk * 8 + lrow8;
      int jg = jl ^ (row & 7);
      gload16(Abase + (size_t)row * K_ + k0 + jg * 8, &sA[chunk * 512]);
    }
    // stage B: wins^T rows are contiguous in xbt
    int t_off = k0 >> 11, nn0 = k0 & 2047;
    for (int ci = 0; ci < 2; ++ci) {
      int chunk = wid * 2 + ci;
      int crow = chunk * 8 + lrow8;
      int jg = jl ^ (crow & 7);
      gload16(Xbase + ((size_t)(t_off * C_ + crow)) * N_ + nn0 + jg * 8, &sB[chunk * 512]);
    }
    __syncthreads();
    for (int kk = 0; kk < 2; ++kk) {
      int gchunk = kk * 4 + l4;
      bf16x8 af[4], bfr[2];
      for (int i = 0; i < 4; ++i) {
        int row = wm * 64 + i * 16 + l15;
        int ch = gchunk ^ (row & 7);
        af[i] = *(const bf16x8*)&sA[row * 64 + ch * 8];
      }
      for (int j = 0; j < 2; ++j) {
        int row = wn * 32 + j * 16 + l15;
        int ch = gchunk ^ (row & 7);
        bfr[j] = *(const bf16x8*)&sB[row * 64 + ch * 8];
      }
      for (int i = 0; i < 4; ++i)
        for (int j = 0; j < 2; ++j)
          acc[i][j] = __builtin_amdgcn_mfma_f32_16x16x32_bf16(af[i], bfr[j], acc[i][j], 0, 0, 0);
    }
  }
  // write agg as bf16 [bw][n][c]
  unsigned short* Obase = aggb + (size_t)bw * N_ * C_;
  for (int i = 0; i < 4; ++i)
    for (int j = 0; j < 2; ++j)
      for (int r = 0; r < 4; ++r) {
        int n = bm * 128 + wm * 64 + i * 16 + l4 * 4 + r;
        int c = wn * 32 + j * 16 + l15;
        Obase[(size_t)n * C_ + c] = f2bf(acc[i][j][r]);
      }
}

// ---------------- epilogue: pre = agg @ W[w,f] + b; glu; max over f ----------------
__global__ __launch_bounds__(256) void glu_out(const unsigned short* __restrict__ aggb,
                                               const unsigned short* __restrict__ wbt,
                                               const float* __restrict__ bias,
                                               float* __restrict__ out) {
  __shared__ __align__(16) unsigned short sW[3 * 128 * 64];  // [f*128+d][c], swizzled
  int bn = blockIdx.x, bw = blockIdx.y;
  int w = bw % NW_;
  int tid = threadIdx.x, lane = tid & 63, wid = tid >> 6;
  int lrow8 = lane >> 3, jl = lane & 7;
  int l15 = lane & 15, l4 = lane >> 4;
  const unsigned short* Wsrc = wbt + (size_t)w * 3 * 128 * 64;
  for (int ci = 0; ci < 12; ++ci) {
    int chunk = wid * 12 + ci;   // 48 chunks total
    int row = chunk * 8 + lrow8;
    int jg = jl ^ (row & 7);
    gload16(Wsrc + (size_t)row * 64 + jg * 8, &sW[chunk * 512]);
  }
  // A-fragments straight from global (bf16 agg)
  const unsigned short* Abase = aggb + ((size_t)bw * N_ + bn * 128 + wid * 32) * C_;
  bf16x8 af[2][2];
  for (int i = 0; i < 2; ++i)
    for (int kh = 0; kh < 2; ++kh)
      af[i][kh] = *(const bf16x8*)(Abase + (size_t)(i * 16 + l15) * C_ + kh * 32 + l4 * 8);
  __syncthreads();

  float omax[2][4][4];
  for (int i = 0; i < 2; ++i)
    for (int j = 0; j < 4; ++j)
      for (int r = 0; r < 4; ++r) omax[i][j][r] = -INFINITY;

  for (int f = 0; f < 3; ++f) {
    f32x4 acc[2][8];
    for (int i = 0; i < 2; ++i)
      for (int j = 0; j < 8; ++j) acc[i][j] = (f32x4)0.f;
    for (int kh = 0; kh < 2; ++kh) {
      int gchunk = kh * 4 + l4;
      for (int j = 0; j < 8; ++j) {
        int row = f * 128 + j * 16 + l15;
        int ch = gchunk ^ (row & 7);
        bf16x8 bfr = *(const bf16x8*)&sW[row * 64 + ch * 8];
        for (int i = 0; i < 2; ++i)
          acc[i][j] = __builtin_amdgcn_mfma_f32_16x16x32_bf16(af[i][kh], bfr, acc[i][j], 0, 0, 0);
      }
    }
    for (int j = 0; j < 4; ++j) {
      float bl = bias[(w * 3 + f) * 128 + j * 16 + l15];
      float br = bias[(w * 3 + f) * 128 + 64 + j * 16 + l15];
      for (int i = 0; i < 2; ++i)
        for (int r = 0; r < 4; ++r) {
          float lhs = acc[i][j][r] + bl;
          float rhs = acc[i][j + 4][r] + br;
          float g = lhs / (1.f + __expf(-rhs));  // lhs * sigmoid(rhs)
          omax[i][j][r] = fmaxf(omax[i][j][r], g);
        }
    }
  }
  float* Obase = out + ((size_t)bw * N_ + bn * 128 + wid * 32) * C_;
  for (int i = 0; i < 2; ++i)
    for (int j = 0; j < 4; ++j)
      for (int r = 0; r < 4; ++r)
        Obase[(size_t)(i * 16 + l4 * 4 + r) * C_ + j * 16 + l15] = omax[i][j][r];
}

extern "C" void kernel_launch(void* const* d_in, const int* in_sizes, int n_in,
                              void* d_out, int out_size, void* d_ws, size_t ws_size,
                              hipStream_t stream) {
  const float* data = (const float*)d_in[0];
  const float* adj  = (const float*)d_in[1];
  const float* temb = (const float*)d_in[2];
  const float* semb = (const float*)d_in[3];
  const float* W    = (const float*)d_in[4];
  const float* bias = (const float*)d_in[5];
  float* out = (float*)d_out;

  char* ws = (char*)d_ws;
  unsigned short* xbt  = (unsigned short*)ws;               // 50,331,648 B
  unsigned short* adjb = (unsigned short*)(ws + 50331648);  // 25,165,824 B
  unsigned short* wbt  = (unsigned short*)(ws + 75497472);  //    491,520 B
  unsigned short* aggb = (unsigned short*)(ws + 75988992);  // 41,943,040 B (total ~118 MB)

  hipLaunchKernelGGL(prep_x,   dim3(16 * T_ * B_), dim3(256), 0, stream, data, temb, semb, xbt);
  hipLaunchKernelGGL(prep_adj, dim3(6144),         dim3(256), 0, stream, adj, adjb);
  hipLaunchKernelGGL(prep_w,   dim3(960),          dim3(256), 0, stream, W, wbt);
  hipLaunchKernelGGL(gemm_agg, dim3(16, 160),      dim3(256), 0, stream, adjb, xbt, aggb);
  hipLaunchKernelGGL(glu_out,  dim3(16, 160),      dim3(256), 0, stream, aggb, wbt, bias, out);
}